// Round 7
// baseline (215.048 us; speedup 1.0000x reference)
//
#include <hip/hip_runtime.h>
#include <utility>

// ConvQuad2D as ONE pure GEMM over packed-f16 pair-features — SINGLE KERNEL.
// r6 post-mortem: main dispatch 69.6us but bench 137us — ~65us gap from the
// prep dispatch + inter-kernel dependency (hypothesis under test). Also
// occupancy 2.8 waves/SIMD (unified VGPR+AGPR ~190) couldn't hide global-B
// L2 latency. r7: prep folded into the main kernel — each block builds all
// 49x64 B-fragments into 50KB LDS (constexpr slot table, ~98 vals/thread),
// one barrier, then K-loop reads bf via ds_read_b128 (imm offset, ~120cyc
// latency). No second dispatch, no rotating register buffer.
// Feature order: slot s in [0,196): s<181 pair slot (i,g), g in [i>>1,12]:
//   features (p_i*p_{2g}, p_i*p_{2g+1}); weights j==i -> Wq[d,i,i],
//   j>i -> Wq[d,i,j]+Wq[d,j,i], else 0. s<194: linear t=s-181: (p_{2t},p_{2t+1})
//   w/ Klin[j,d,o] (j==25 -> 0). else pad. k-slot: chunk c=s>>2, lane q=d.

typedef _Float16 half2 __attribute__((ext_vector_type(2)));
typedef _Float16 half4 __attribute__((ext_vector_type(4)));
typedef _Float16 half8 __attribute__((ext_vector_type(8)));
typedef float floatx4 __attribute__((ext_vector_type(4)));

#define BB 8
#define HH 250
#define WW 250
#define NPIX (BB * HH * WW)   // 500,000
#define NF 16
#define NSLOT_PAIR 181
#define NSLOT_LIN  13
#define NCHUNK     49         // 49*4 = 196 half2 slots = 392 features/channel
#define NFRAG      (NCHUNK * 64)   // 3136 B-fragments in LDS

__host__ __device__ constexpr int slot_i(int s) {
    int i = 0, base = 0;
    while (base + (13 - (i >> 1)) <= s) { base += 13 - (i >> 1); ++i; }
    return i;
}
__host__ __device__ constexpr int slot_g(int s) {
    int i = 0, base = 0;
    while (base + (13 - (i >> 1)) <= s) { base += 13 - (i >> 1); ++i; }
    return (i >> 1) + (s - base);
}

// runtime lookup table for the B-build phase (no while-loops in device code)
struct SlotTab { unsigned char i[NSLOT_PAIR]; unsigned char g[NSLOT_PAIR]; };
__host__ __device__ constexpr SlotTab make_tab() {
    SlotTab t{};
    int s = 0;
    for (int i = 0; i < 25; ++i)
        for (int g = (i >> 1); g < 13; ++g) { t.i[s] = (unsigned char)i; t.g[s] = (unsigned char)g; ++s; }
    return t;
}
__device__ constexpr SlotTab kTab = make_tab();

// ---------- packed helpers ----------
__device__ __forceinline__ half2 pk(float lo, float hi) {
    return __builtin_bit_cast(half2, __builtin_amdgcn_cvt_pkrtz(lo, hi));
}

template<int S>
__device__ __forceinline__ half2 slotval(const half2 (&pd2)[13]) {
    if constexpr (S < NSLOT_PAIR) {
        constexpr int i = slot_i(S), g = slot_g(S);
        constexpr int ir = i >> 1, ih = i & 1;
        const half2 src = pd2[ir];
        const half2 bi = {src[ih], src[ih]};   // op_sel broadcast
        return bi * pd2[g];                    // v_pk_mul_f16
    } else if constexpr (S < NSLOT_PAIR + NSLOT_LIN) {
        return pd2[S - NSLOT_PAIR];
    } else {
        return half2{(_Float16)0.f, (_Float16)0.f};
    }
}

template<int C>
__device__ __forceinline__ half8 make_frag(const half2 (&pd2)[13]) {
    const half2 a0 = slotval<C * 4 + 0>(pd2);
    const half2 a1 = slotval<C * 4 + 1>(pd2);
    const half2 a2 = slotval<C * 4 + 2>(pd2);
    const half2 a3 = slotval<C * 4 + 3>(pd2);
    const half4 lo = __builtin_shufflevector(a0, a1, 0, 1, 2, 3);
    const half4 hi = __builtin_shufflevector(a2, a3, 0, 1, 2, 3);
    return __builtin_shufflevector(lo, hi, 0, 1, 2, 3, 4, 5, 6, 7);
}

template<size_t... Cs>
__device__ __forceinline__ void gemm_all(
    const half2 (&p0)[13], const half2 (&p1)[13],
    const half2 (&p2)[13], const half2 (&p3)[13],
    const _Float16* sBlane,
    floatx4& a0, floatx4& a1, floatx4& a2, floatx4& a3,
    std::index_sequence<Cs...>) {
    (([&] {
        constexpr int C = (int)Cs;
        const half8 bf = *(const half8*)(sBlane + C * 64 * 8);  // ds_read_b128, imm offset
        a0 = __builtin_amdgcn_mfma_f32_16x16x32_f16(make_frag<C>(p0), bf, a0, 0, 0, 0);
        a1 = __builtin_amdgcn_mfma_f32_16x16x32_f16(make_frag<C>(p1), bf, a1, 0, 0, 0);
        a2 = __builtin_amdgcn_mfma_f32_16x16x32_f16(make_frag<C>(p2), bf, a2, 0, 0, 0);
        a3 = __builtin_amdgcn_mfma_f32_16x16x32_f16(make_frag<C>(p3), bf, a3, 0, 0, 0);
    }()), ...);
}

// ---------- patch -> 13 half2 registers ----------
__device__ __forceinline__ void build_patch(const float* __restrict__ x,
                                            int pix, int q, half2 (&pd2)[13]) {
    const int pixc = min(pix, NPIX - 1);
    const int w  = pixc % WW;
    const int t1 = pixc / WW;
    const int h  = t1 % HH;
    const int b  = t1 / HH;
    float pf[26];
    pf[25] = 0.f;
    #pragma unroll
    for (int kh = 0; kh < 5; ++kh) {
        const int r = h + kh - 2;
        const float rm = (r >= 0 && r < HH) ? 1.f : 0.f;
        const int rc = min(max(r, 0), HH - 1);
        const int rowb = ((b * HH + rc) * WW) * 4;
        #pragma unroll
        for (int kw = 0; kw < 5; ++kw) {
            const int c = w + kw - 2;
            const float cm = (c >= 0 && c < WW) ? 1.f : 0.f;
            const int cc = min(max(c, 0), WW - 1);
            pf[kh * 5 + kw] = x[rowb + cc * 4 + q] * (rm * cm);
        }
    }
    #pragma unroll
    for (int t = 0; t < 13; ++t) pd2[t] = pk(pf[2 * t], pf[2 * t + 1]);
}

// ---------- main kernel: 64 pixels per wave, B built in LDS, one barrier ----------
__global__ __launch_bounds__(256) void convquad_gemm(
    const float* __restrict__ x,       // (8,250,250,4)
    const float* __restrict__ lin_w,   // (5,5,4,16)
    const float* __restrict__ quad_w,  // (4,25,25,16)
    const float* __restrict__ bias,    // (16,)
    float* __restrict__ out)           // (8,250,250,16)
{
    __shared__ _Float16 sB[NFRAG * 8];  // 50,176 B

    // ---- phase 1: cooperative B-fragment build (98 halfs/thread) ----
    #pragma unroll 2
    for (int k = 0; k < 13; ++k) {
        const int idx = threadIdx.x + k * 256;
        if (idx < NFRAG) {
            const int c  = idx >> 6, ln = idx & 63;
            const int n  = ln & 15,  d  = ln >> 4;
            half8 frag;
            #pragma unroll
            for (int e = 0; e < 8; ++e) {
                const int f = c * 8 + e;
                const int s = f >> 1, hf = f & 1;
                float v = 0.f;
                if (s < NSLOT_PAIR) {
                    const int i = kTab.i[s];
                    const int j = 2 * (int)kTab.g[s] + hf;
                    if (j == i)
                        v = quad_w[((d * 25 + i) * 25 + i) * 16 + n];
                    else if (j > i && j < 25)
                        v = quad_w[((d * 25 + i) * 25 + j) * 16 + n]
                          + quad_w[((d * 25 + j) * 25 + i) * 16 + n];
                } else if (s < NSLOT_PAIR + NSLOT_LIN) {
                    const int j = 2 * (s - NSLOT_PAIR) + hf;
                    if (j < 25) v = lin_w[(j * 4 + d) * 16 + n];
                }
                frag[e] = (_Float16)v;
            }
            *(half8*)(sB + idx * 8) = frag;
        }
    }

    // ---- phase 2: per-lane patches (4 pixel-tiles) ----
    const int lane = threadIdx.x & 63;
    const int m = lane & 15;     // pixel-in-tile (A row); also o for the store
    const int q = lane >> 4;     // channel d for A; row-quad for D
    const int pixbase = blockIdx.x * 256 + (threadIdx.x >> 6) * 64;

    half2 pdA[13], pdB[13], pdC[13], pdD[13];
    build_patch(x, pixbase +  0 + m, q, pdA);
    build_patch(x, pixbase + 16 + m, q, pdB);
    build_patch(x, pixbase + 32 + m, q, pdC);
    build_patch(x, pixbase + 48 + m, q, pdD);

    __syncthreads();

    // ---- phase 3: GEMM over 49 chunks ----
    const float bo = bias[m];
    floatx4 acc0 = {bo, bo, bo, bo};   // bias folded into MFMA C-init
    floatx4 acc1 = acc0, acc2 = acc0, acc3 = acc0;

    gemm_all(pdA, pdB, pdC, pdD, sB + lane * 8,
             acc0, acc1, acc2, acc3, std::make_index_sequence<NCHUNK>{});

    #pragma unroll
    for (int r = 0; r < 4; ++r) {
        const int p0 = pixbase +  0 + q * 4 + r;
        if (p0 < NPIX) out[p0 * NF + m] = acc0[r];
        const int p1 = pixbase + 16 + q * 4 + r;
        if (p1 < NPIX) out[p1 * NF + m] = acc1[r];
        const int p2 = pixbase + 32 + q * 4 + r;
        if (p2 < NPIX) out[p2 * NF + m] = acc2[r];
        const int p3 = pixbase + 48 + q * 4 + r;
        if (p3 < NPIX) out[p3 * NF + m] = acc3[r];
    }
}

extern "C" void kernel_launch(void* const* d_in, const int* in_sizes, int n_in,
                              void* d_out, int out_size, void* d_ws, size_t ws_size,
                              hipStream_t stream) {
    const float* x      = (const float*)d_in[0];
    const float* lin_w  = (const float*)d_in[1];
    const float* quad_w = (const float*)d_in[2];
    const float* bias   = (const float*)d_in[3];
    float* out = (float*)d_out;

    const int nblocks = (NPIX + 255) / 256;   // 1954 blocks, 64 pix/wave
    convquad_gemm<<<dim3(nblocks), dim3(256), 0, stream>>>(x, lin_w, quad_w, bias, out);
}

// Round 8
// 134.989 us; speedup vs baseline: 1.5931x; 1.5931x over previous
//
#include <hip/hip_runtime.h>
#include <utility>

// ConvQuad2D as ONE pure GEMM over packed-f16 pair-features. Two kernels:
// cheap prep (49 blocks) builds B-fragments; main kernel block-copies them
// to LDS (coalesced, 50KB) and runs the K-loop off ds_read_b128.
// r7 post-mortem: per-block B *computation* cost ~120us of scattered loads ->
// reverted to prep kernel. Bench-vs-dispatch gap (~45-65us) persists with a
// single kernel -> fixed harness overhead, optimize the main dispatch.
// r8 changes vs r6 (69.6us main): (1) B from LDS not global (120cyc vs 200-900,
// no vmcnt in K-loop); (2) 512-thr blocks + 50KB LDS -> 3 blocks/CU = 6
// waves/SIMD (vs 2.8), 2 tiles/wave keeps VGPR<=~64; (3) wave-uniform interior
// fast-path for patch build (no clamps/masks, imm-offset loads) ~ -18% VALU.
// Feature order (prep owns matching weights): slot s in [0,196):
//   s<181: pair (i,g), g in [i>>1,12]: (p_i*p_{2g}, p_i*p_{2g+1});
//          weights: j==i -> Wq[d,i,i]; j>i -> Wq[d,i,j]+Wq[d,j,i]; else 0
//   s<194: linear t=s-181: (p_{2t},p_{2t+1}) w/ Klin[j,d,o] (j==25 -> 0); else pad.
// k-slot: chunk c=s>>2, lane q = channel d, e = feature-in-chunk.

typedef _Float16 half2 __attribute__((ext_vector_type(2)));
typedef _Float16 half4 __attribute__((ext_vector_type(4)));
typedef _Float16 half8 __attribute__((ext_vector_type(8)));
typedef float floatx4 __attribute__((ext_vector_type(4)));

#define BB 8
#define HH 250
#define WW 250
#define NPIX (BB * HH * WW)   // 500,000
#define NF 16
#define NSLOT_PAIR 181
#define NSLOT_LIN  13
#define NCHUNK     49              // 49*4 = 196 half2 slots = 392 features/channel
#define NFRAG      (NCHUNK * 64)   // 3136 B-fragments

__host__ __device__ constexpr int slot_i(int s) {
    int i = 0, base = 0;
    while (base + (13 - (i >> 1)) <= s) { base += 13 - (i >> 1); ++i; }
    return i;
}
__host__ __device__ constexpr int slot_g(int s) {
    int i = 0, base = 0;
    while (base + (13 - (i >> 1)) <= s) { base += 13 - (i >> 1); ++i; }
    return (i >> 1) + (s - base);
}

// ---------- pre-pass: B fragments in MFMA lane order ----------
__global__ void prep_frags(const float* __restrict__ lin_w,   // (5,5,4,16)
                           const float* __restrict__ quad_w,  // (4,25,25,16)
                           _Float16* __restrict__ fragB) {
    const int c = blockIdx.x;       // 0..48
    const int lane = threadIdx.x;   // 0..63
    const int n = lane & 15;
    const int d = lane >> 4;
    half8 frag;
    #pragma unroll
    for (int e = 0; e < 8; ++e) {
        const int f = c * 8 + e;
        const int s = f >> 1, hf = f & 1;
        float v = 0.f;
        if (s < NSLOT_PAIR) {
            int i = 0, base = 0;
            while (base + (13 - (i >> 1)) <= s) { base += 13 - (i >> 1); ++i; }
            const int g = (i >> 1) + (s - base);
            const int j = 2 * g + hf;
            if (j == i)
                v = quad_w[((d * 25 + i) * 25 + i) * 16 + n];
            else if (j > i && j < 25)
                v = quad_w[((d * 25 + i) * 25 + j) * 16 + n]
                  + quad_w[((d * 25 + j) * 25 + i) * 16 + n];
        } else if (s < NSLOT_PAIR + NSLOT_LIN) {
            const int j = 2 * (s - NSLOT_PAIR) + hf;
            if (j < 25) v = lin_w[(j * 4 + d) * 16 + n];
        }
        frag[e] = (_Float16)v;
    }
    *(half8*)(fragB + (c * 64 + lane) * 8) = frag;
}

// ---------- packed helpers ----------
__device__ __forceinline__ half2 pk(float lo, float hi) {
    return __builtin_bit_cast(half2, __builtin_amdgcn_cvt_pkrtz(lo, hi));
}

template<int S>
__device__ __forceinline__ half2 slotval(const half2 (&pd2)[13]) {
    if constexpr (S < NSLOT_PAIR) {
        constexpr int i = slot_i(S), g = slot_g(S);
        constexpr int ir = i >> 1, ih = i & 1;
        const half2 src = pd2[ir];
        const half2 bi = {src[ih], src[ih]};   // op_sel broadcast
        return bi * pd2[g];                    // v_pk_mul_f16
    } else if constexpr (S < NSLOT_PAIR + NSLOT_LIN) {
        return pd2[S - NSLOT_PAIR];
    } else {
        return half2{(_Float16)0.f, (_Float16)0.f};
    }
}

template<int C>
__device__ __forceinline__ half8 make_frag(const half2 (&pd2)[13]) {
    const half2 a0 = slotval<C * 4 + 0>(pd2);
    const half2 a1 = slotval<C * 4 + 1>(pd2);
    const half2 a2 = slotval<C * 4 + 2>(pd2);
    const half2 a3 = slotval<C * 4 + 3>(pd2);
    const half4 lo = __builtin_shufflevector(a0, a1, 0, 1, 2, 3);
    const half4 hi = __builtin_shufflevector(a2, a3, 0, 1, 2, 3);
    return __builtin_shufflevector(lo, hi, 0, 1, 2, 3, 4, 5, 6, 7);
}

template<size_t... Cs>
__device__ __forceinline__ void gemm_all(
    const half2 (&p0)[13], const half2 (&p1)[13],
    const _Float16* sBlane,
    floatx4& a0, floatx4& a1,
    std::index_sequence<Cs...>) {
    (([&] {
        constexpr int C = (int)Cs;
        const half8 bf = *(const half8*)(sBlane + C * 64 * 8);  // ds_read_b128 imm
        a0 = __builtin_amdgcn_mfma_f32_16x16x32_f16(make_frag<C>(p0), bf, a0, 0, 0, 0);
        a1 = __builtin_amdgcn_mfma_f32_16x16x32_f16(make_frag<C>(p1), bf, a1, 0, 0, 0);
    }()), ...);
}

// ---------- patch builders ----------
__device__ __forceinline__ void coords(int pix, int& b, int& h, int& w) {
    const int pixc = min(pix, NPIX - 1);
    w = pixc % WW;
    const int t = pixc / WW;
    h = t % HH;
    b = t / HH;
}

// interior: all 25 taps in-bounds; base + imm offsets, no masks/clamps
__device__ __forceinline__ void build_patch_fast(const float* __restrict__ x,
                                                 int b, int h, int w, int q,
                                                 half2 (&pd2)[13]) {
    const float* base = x + (((b * HH + h - 2) * WW) + (w - 2)) * 4 + q;
    float pf[26];
    pf[25] = 0.f;
    #pragma unroll
    for (int kh = 0; kh < 5; ++kh)
        #pragma unroll
        for (int kw = 0; kw < 5; ++kw)
            pf[kh * 5 + kw] = base[(kh * WW + kw) * 4];
    #pragma unroll
    for (int t = 0; t < 13; ++t) pd2[t] = pk(pf[2 * t], pf[2 * t + 1]);
}

__device__ __forceinline__ void build_patch_slow(const float* __restrict__ x,
                                                 int b, int h, int w, int q,
                                                 half2 (&pd2)[13]) {
    float pf[26];
    pf[25] = 0.f;
    #pragma unroll
    for (int kh = 0; kh < 5; ++kh) {
        const int r = h + kh - 2;
        const float rm = (r >= 0 && r < HH) ? 1.f : 0.f;
        const int rc = min(max(r, 0), HH - 1);
        const int rowb = ((b * HH + rc) * WW) * 4;
        #pragma unroll
        for (int kw = 0; kw < 5; ++kw) {
            const int c = w + kw - 2;
            const float cm = (c >= 0 && c < WW) ? 1.f : 0.f;
            const int cc = min(max(c, 0), WW - 1);
            pf[kh * 5 + kw] = x[rowb + cc * 4 + q] * (rm * cm);
        }
    }
    #pragma unroll
    for (int t = 0; t < 13; ++t) pd2[t] = pk(pf[2 * t], pf[2 * t + 1]);
}

// ---------- main kernel: 512 threads, 32 pix/wave, B copied to LDS ----------
__global__ __launch_bounds__(512, 6) void convquad_gemm(
    const float* __restrict__ x,       // (8,250,250,4)
    const float* __restrict__ bias,    // (16,)
    const _Float16* __restrict__ fragB,
    float* __restrict__ out)           // (8,250,250,16)
{
    __shared__ __align__(16) _Float16 sB[NFRAG * 8];  // 50,176 B

    {   // coalesced 50KB copy: global (L2-resident) -> LDS
        const float4* src = (const float4*)fragB;
        float4* dst = (float4*)sB;
        #pragma unroll
        for (int t = threadIdx.x; t < NFRAG * 8 / 8; t += 512) dst[t] = src[t];
    }

    const int lane = threadIdx.x & 63;
    const int m = lane & 15;     // pixel-in-tile (A row); also o for the store
    const int q = lane >> 4;     // channel d for A; row-quad for D
    const int pixbase = blockIdx.x * 256 + (threadIdx.x >> 6) * 32;

    int b0, h0, w0, b1, h1, w1;
    coords(pixbase + m,      b0, h0, w0);
    coords(pixbase + 16 + m, b1, h1, w1);

    half2 pd0[13], pd1[13];
    const bool interior =
        h0 >= 2 && h0 < HH - 2 && w0 >= 2 && w0 < WW - 2 &&
        h1 >= 2 && h1 < HH - 2 && w1 >= 2 && w1 < WW - 2;
    if (__all(interior)) {
        build_patch_fast(x, b0, h0, w0, q, pd0);
        build_patch_fast(x, b1, h1, w1, q, pd1);
    } else {
        build_patch_slow(x, b0, h0, w0, q, pd0);
        build_patch_slow(x, b1, h1, w1, q, pd1);
    }

    __syncthreads();

    const float bo = bias[m];
    floatx4 acc0 = {bo, bo, bo, bo};   // bias folded into MFMA C-init
    floatx4 acc1 = acc0;

    gemm_all(pd0, pd1, sB + lane * 8, acc0, acc1,
             std::make_index_sequence<NCHUNK>{});

    #pragma unroll
    for (int r = 0; r < 4; ++r) {
        const int p0 = pixbase + q * 4 + r;
        if (p0 < NPIX) out[p0 * NF + m] = acc0[r];
        const int p1 = pixbase + 16 + q * 4 + r;
        if (p1 < NPIX) out[p1 * NF + m] = acc1[r];
    }
}

extern "C" void kernel_launch(void* const* d_in, const int* in_sizes, int n_in,
                              void* d_out, int out_size, void* d_ws, size_t ws_size,
                              hipStream_t stream) {
    const float* x      = (const float*)d_in[0];
    const float* lin_w  = (const float*)d_in[1];
    const float* quad_w = (const float*)d_in[2];
    const float* bias   = (const float*)d_in[3];
    float* out = (float*)d_out;
    _Float16* fragB = (_Float16*)d_ws;   // 50,176 B

    prep_frags<<<dim3(NCHUNK), dim3(64), 0, stream>>>(lin_w, quad_w, fragB);

    const int nblocks = (NPIX + 255) / 256;   // 1954 blocks, 256 pix/block
    convquad_gemm<<<dim3(nblocks), dim3(512), 0, stream>>>(x, bias, fragB, out);
}

// Round 9
// 105.505 us; speedup vs baseline: 2.0383x; 1.2795x over previous
//
#include <hip/hip_runtime.h>
#include <utility>

// ConvQuad2D as ONE pure GEMM over packed-f16 pair-features.
// r8 post-mortem: wall pinned ~70us across global-B/LDS-B/occupancy variants;
// pipe-busy sums ~35% -> waves asleep >90%. Common factor: per-lane x-patch
// gather (50 scalar global loads/wave, ~100KB lines/block >> 32KB L1) ->
// L2-latency + MSHR serialization. r9: 2D tile 32w x 8h per 512-thr block;
// haloed 36x12 x-tile staged ONCE to 6.9KB LDS [c][h][w] (7 float4 wave-loads
// per block, borders zeroed at staging). Patch build = 25 imm-offset
// ds_read_b32 + 13 cvt_pkrtz, no masks. B stays in global (L1/L2-hot, same
// address stream for all waves); LDS small -> 24 waves/CU (launch_bounds 512,6).
// Feature order (prep owns matching weights): slot s in [0,196):
//   s<181: pair (i,g), g in [i>>1,12]: (p_i*p_{2g}, p_i*p_{2g+1});
//          weights: j==i -> Wq[d,i,i]; j>i -> Wq[d,i,j]+Wq[d,j,i]; else 0
//   s<194: linear t=s-181: (p_{2t},p_{2t+1}) w/ Klin[j,d,o] (j==25 -> 0); else pad.
// k-slot: chunk c=s>>2, lane q = channel d, e = feature-in-chunk.

typedef _Float16 half2 __attribute__((ext_vector_type(2)));
typedef _Float16 half4 __attribute__((ext_vector_type(4)));
typedef _Float16 half8 __attribute__((ext_vector_type(8)));
typedef float floatx4 __attribute__((ext_vector_type(4)));

#define BB 8
#define HH 250
#define WW 250
#define NF 16
#define NSLOT_PAIR 181
#define NSLOT_LIN  13
#define NCHUNK     49         // 49*4 = 196 half2 slots = 392 features/channel

#define TW 32                 // tile width  (pixels)
#define TH 8                  // tile height (= waves/block)
#define XW (TW + 4)           // 36 staged cols
#define XH (TH + 4)           // 12 staged rows
#define XSZ (XW * XH)         // 432 positions

__host__ __device__ constexpr int slot_i(int s) {
    int i = 0, base = 0;
    while (base + (13 - (i >> 1)) <= s) { base += 13 - (i >> 1); ++i; }
    return i;
}
__host__ __device__ constexpr int slot_g(int s) {
    int i = 0, base = 0;
    while (base + (13 - (i >> 1)) <= s) { base += 13 - (i >> 1); ++i; }
    return (i >> 1) + (s - base);
}

// ---------- pre-pass: B fragments in MFMA lane order ----------
__global__ void prep_frags(const float* __restrict__ lin_w,   // (5,5,4,16)
                           const float* __restrict__ quad_w,  // (4,25,25,16)
                           _Float16* __restrict__ fragB) {
    const int c = blockIdx.x;       // 0..48
    const int lane = threadIdx.x;   // 0..63
    const int n = lane & 15;
    const int d = lane >> 4;
    half8 frag;
    #pragma unroll
    for (int e = 0; e < 8; ++e) {
        const int f = c * 8 + e;
        const int s = f >> 1, hf = f & 1;
        float v = 0.f;
        if (s < NSLOT_PAIR) {
            int i = 0, base = 0;
            while (base + (13 - (i >> 1)) <= s) { base += 13 - (i >> 1); ++i; }
            const int g = (i >> 1) + (s - base);
            const int j = 2 * g + hf;
            if (j == i)
                v = quad_w[((d * 25 + i) * 25 + i) * 16 + n];
            else if (j > i && j < 25)
                v = quad_w[((d * 25 + i) * 25 + j) * 16 + n]
                  + quad_w[((d * 25 + j) * 25 + i) * 16 + n];
        } else if (s < NSLOT_PAIR + NSLOT_LIN) {
            const int j = 2 * (s - NSLOT_PAIR) + hf;
            if (j < 25) v = lin_w[(j * 4 + d) * 16 + n];
        }
        frag[e] = (_Float16)v;
    }
    *(half8*)(fragB + (c * 64 + lane) * 8) = frag;
}

// ---------- packed helpers ----------
__device__ __forceinline__ half2 pk(float lo, float hi) {
    return __builtin_bit_cast(half2, __builtin_amdgcn_cvt_pkrtz(lo, hi));
}

template<int S>
__device__ __forceinline__ half2 slotval(const half2 (&pd2)[13]) {
    if constexpr (S < NSLOT_PAIR) {
        constexpr int i = slot_i(S), g = slot_g(S);
        constexpr int ir = i >> 1, ih = i & 1;
        const half2 src = pd2[ir];
        const half2 bi = {src[ih], src[ih]};   // op_sel broadcast
        return bi * pd2[g];                    // v_pk_mul_f16
    } else if constexpr (S < NSLOT_PAIR + NSLOT_LIN) {
        return pd2[S - NSLOT_PAIR];
    } else {
        return half2{(_Float16)0.f, (_Float16)0.f};
    }
}

template<int C>
__device__ __forceinline__ half8 make_frag(const half2 (&pd2)[13]) {
    const half2 a0 = slotval<C * 4 + 0>(pd2);
    const half2 a1 = slotval<C * 4 + 1>(pd2);
    const half2 a2 = slotval<C * 4 + 2>(pd2);
    const half2 a3 = slotval<C * 4 + 3>(pd2);
    const half4 lo = __builtin_shufflevector(a0, a1, 0, 1, 2, 3);
    const half4 hi = __builtin_shufflevector(a2, a3, 0, 1, 2, 3);
    return __builtin_shufflevector(lo, hi, 0, 1, 2, 3, 4, 5, 6, 7);
}

template<size_t... Cs>
__device__ __forceinline__ void gemm_all(
    const half2 (&p0)[13], const half2 (&p1)[13],
    const _Float16* __restrict__ fb,
    floatx4& a0, floatx4& a1,
    std::index_sequence<Cs...>) {
    (([&] {
        constexpr int C = (int)Cs;
        const half8 bf = *(const half8*)(fb + C * 64 * 8);  // global, L1/L2-hot
        a0 = __builtin_amdgcn_mfma_f32_16x16x32_f16(make_frag<C>(p0), bf, a0, 0, 0, 0);
        a1 = __builtin_amdgcn_mfma_f32_16x16x32_f16(make_frag<C>(p1), bf, a1, 0, 0, 0);
    }()), ...);
}

// ---------- patch from LDS x-tile: 25 imm-offset ds_reads + 13 cvt ----------
__device__ __forceinline__ void patch_from_lds(const float* xt, int base,
                                               half2 (&pd2)[13]) {
    float pf[26];
    pf[25] = 0.f;
    #pragma unroll
    for (int kh = 0; kh < 5; ++kh)
        #pragma unroll
        for (int kw = 0; kw < 5; ++kw)
            pf[kh * 5 + kw] = xt[base + kh * XW + kw];
    #pragma unroll
    for (int t = 0; t < 13; ++t) pd2[t] = pk(pf[2 * t], pf[2 * t + 1]);
}

// ---------- main kernel: 512 thr = 8 waves = 8 rows x 32 cols ----------
__global__ __launch_bounds__(512, 6) void convquad_gemm(
    const float* __restrict__ x,       // (8,250,250,4)
    const float* __restrict__ bias,    // (16,)
    const _Float16* __restrict__ fragB,
    float* __restrict__ out)           // (8,250,250,16)
{
    __shared__ float xt[4 * XSZ];      // 6,912 B: [c][hh][ww]

    const int w0 = blockIdx.x * TW;
    const int h0 = blockIdx.y * TH;
    const int b  = blockIdx.z;

    // ---- stage haloed x-tile (borders zeroed -> no masks later) ----
    {
        const int p = threadIdx.x;
        if (p < XSZ) {
            const int hh = p / XW, ww = p % XW;
            const int r = h0 + hh - 2, c = w0 + ww - 2;
            float4 v = make_float4(0.f, 0.f, 0.f, 0.f);
            if ((unsigned)r < (unsigned)HH && (unsigned)c < (unsigned)WW)
                v = ((const float4*)x)[(b * HH + r) * WW + c];
            xt[0 * XSZ + p] = v.x;
            xt[1 * XSZ + p] = v.y;
            xt[2 * XSZ + p] = v.z;
            xt[3 * XSZ + p] = v.w;
        }
    }
    __syncthreads();

    const int lane = threadIdx.x & 63;
    const int wave = threadIdx.x >> 6;   // row within tile
    const int m = lane & 15;             // pixel within 16-col segment; also o
    const int q = lane >> 4;             // channel for A; row-quad for D

    // two 16-col segments per wave (cols 0..15, 16..31)
    const int base0 = q * XSZ + wave * XW + m;
    half2 pd0[13], pd1[13];
    patch_from_lds(xt, base0,      pd0);
    patch_from_lds(xt, base0 + 16, pd1);

    const float bo = bias[m];
    floatx4 acc0 = {bo, bo, bo, bo};
    floatx4 acc1 = acc0;

    gemm_all(pd0, pd1, fragB + lane * 8, acc0, acc1,
             std::make_index_sequence<NCHUNK>{});

    // ---- store: pixel w-offset = seg*16 + q*4 + r, o = m ----
    const int h = h0 + wave;
    if (h < HH) {
        const int rowbase = (b * HH + h) * WW;
        #pragma unroll
        for (int r = 0; r < 4; ++r) {
            const int wA = w0 + q * 4 + r;
            if (wA < WW) out[(rowbase + wA) * NF + m] = acc0[r];
            const int wB = w0 + 16 + q * 4 + r;
            if (wB < WW) out[(rowbase + wB) * NF + m] = acc1[r];
        }
    }
}

extern "C" void kernel_launch(void* const* d_in, const int* in_sizes, int n_in,
                              void* d_out, int out_size, void* d_ws, size_t ws_size,
                              hipStream_t stream) {
    const float* x      = (const float*)d_in[0];
    const float* lin_w  = (const float*)d_in[1];
    const float* quad_w = (const float*)d_in[2];
    const float* bias   = (const float*)d_in[3];
    float* out = (float*)d_out;
    _Float16* fragB = (_Float16*)d_ws;   // 50,176 B

    prep_frags<<<dim3(NCHUNK), dim3(64), 0, stream>>>(lin_w, quad_w, fragB);

    dim3 grid((WW + TW - 1) / TW, (HH + TH - 1) / TH, BB);   // 8 x 32 x 8 = 2048
    convquad_gemm<<<grid, dim3(512), 0, stream>>>(x, bias, fragB, out);
}

// Round 10
// 102.149 us; speedup vs baseline: 2.1052x; 1.0328x over previous
//
#include <hip/hip_runtime.h>
#include <utility>

// ConvQuad2D as ONE pure GEMM over packed-f16 pair-features.
// r9 post-mortem: x-tile staging fixed the gather (main ~40us); the ~60us
// bench-vs-dispatch gap is harness re-poison fills (fillBufferAligned 262MB
// ~43us) + launch overhead — not controllable. Remaining main-kernel stall:
// every wave re-reads the full 50KB fragB from global (49x64x16B/wave) ->
// ~800MB of L1-thrashing L2 traffic ~= 23us serialized. r10: stage fragB to
// LDS once per block (102MB total, ~3us) + keep r9 x-tile. LDS 57KB -> 2
// blocks/CU = 4 waves/SIMD (r8 proved survivable once gather is gone).
// K-loop B reads: conflict-free ds_read_b128 (r8: 0 conflicts, same layout).
// Feature order (prep owns matching weights): slot s in [0,196):
//   s<181: pair (i,g), g in [i>>1,12]: (p_i*p_{2g}, p_i*p_{2g+1});
//          weights: j==i -> Wq[d,i,i]; j>i -> Wq[d,i,j]+Wq[d,j,i]; else 0
//   s<194: linear t=s-181: (p_{2t},p_{2t+1}) w/ Klin[j,d,o] (j==25 -> 0); else pad.
// k-slot: chunk c=s>>2, lane q = channel d, e = feature-in-chunk.

typedef _Float16 half2 __attribute__((ext_vector_type(2)));
typedef _Float16 half4 __attribute__((ext_vector_type(4)));
typedef _Float16 half8 __attribute__((ext_vector_type(8)));
typedef float floatx4 __attribute__((ext_vector_type(4)));

#define BB 8
#define HH 250
#define WW 250
#define NF 16
#define NSLOT_PAIR 181
#define NSLOT_LIN  13
#define NCHUNK     49              // 49*4 = 196 half2 slots = 392 features/channel
#define NFRAG      (NCHUNK * 64)   // 3136 B-fragments = 50,176 B

#define TW 32                 // tile width  (pixels)
#define TH 8                  // tile height (= waves/block)
#define XW (TW + 4)           // 36 staged cols
#define XH (TH + 4)           // 12 staged rows
#define XSZ (XW * XH)         // 432 positions

__host__ __device__ constexpr int slot_i(int s) {
    int i = 0, base = 0;
    while (base + (13 - (i >> 1)) <= s) { base += 13 - (i >> 1); ++i; }
    return i;
}
__host__ __device__ constexpr int slot_g(int s) {
    int i = 0, base = 0;
    while (base + (13 - (i >> 1)) <= s) { base += 13 - (i >> 1); ++i; }
    return (i >> 1) + (s - base);
}

// ---------- pre-pass: B fragments in MFMA lane order ----------
__global__ void prep_frags(const float* __restrict__ lin_w,   // (5,5,4,16)
                           const float* __restrict__ quad_w,  // (4,25,25,16)
                           _Float16* __restrict__ fragB) {
    const int c = blockIdx.x;       // 0..48
    const int lane = threadIdx.x;   // 0..63
    const int n = lane & 15;
    const int d = lane >> 4;
    half8 frag;
    #pragma unroll
    for (int e = 0; e < 8; ++e) {
        const int f = c * 8 + e;
        const int s = f >> 1, hf = f & 1;
        float v = 0.f;
        if (s < NSLOT_PAIR) {
            int i = 0, base = 0;
            while (base + (13 - (i >> 1)) <= s) { base += 13 - (i >> 1); ++i; }
            const int g = (i >> 1) + (s - base);
            const int j = 2 * g + hf;
            if (j == i)
                v = quad_w[((d * 25 + i) * 25 + i) * 16 + n];
            else if (j > i && j < 25)
                v = quad_w[((d * 25 + i) * 25 + j) * 16 + n]
                  + quad_w[((d * 25 + j) * 25 + i) * 16 + n];
        } else if (s < NSLOT_PAIR + NSLOT_LIN) {
            const int j = 2 * (s - NSLOT_PAIR) + hf;
            if (j < 25) v = lin_w[(j * 4 + d) * 16 + n];
        }
        frag[e] = (_Float16)v;
    }
    *(half8*)(fragB + (c * 64 + lane) * 8) = frag;
}

// ---------- packed helpers ----------
__device__ __forceinline__ half2 pk(float lo, float hi) {
    return __builtin_bit_cast(half2, __builtin_amdgcn_cvt_pkrtz(lo, hi));
}

template<int S>
__device__ __forceinline__ half2 slotval(const half2 (&pd2)[13]) {
    if constexpr (S < NSLOT_PAIR) {
        constexpr int i = slot_i(S), g = slot_g(S);
        constexpr int ir = i >> 1, ih = i & 1;
        const half2 src = pd2[ir];
        const half2 bi = {src[ih], src[ih]};   // op_sel broadcast
        return bi * pd2[g];                    // v_pk_mul_f16
    } else if constexpr (S < NSLOT_PAIR + NSLOT_LIN) {
        return pd2[S - NSLOT_PAIR];
    } else {
        return half2{(_Float16)0.f, (_Float16)0.f};
    }
}

template<int C>
__device__ __forceinline__ half8 make_frag(const half2 (&pd2)[13]) {
    const half2 a0 = slotval<C * 4 + 0>(pd2);
    const half2 a1 = slotval<C * 4 + 1>(pd2);
    const half2 a2 = slotval<C * 4 + 2>(pd2);
    const half2 a3 = slotval<C * 4 + 3>(pd2);
    const half4 lo = __builtin_shufflevector(a0, a1, 0, 1, 2, 3);
    const half4 hi = __builtin_shufflevector(a2, a3, 0, 1, 2, 3);
    return __builtin_shufflevector(lo, hi, 0, 1, 2, 3, 4, 5, 6, 7);
}

template<size_t... Cs>
__device__ __forceinline__ void gemm_all(
    const half2 (&p0)[13], const half2 (&p1)[13],
    const _Float16* sBlane,
    floatx4& a0, floatx4& a1,
    std::index_sequence<Cs...>) {
    (([&] {
        constexpr int C = (int)Cs;
        const half8 bf = *(const half8*)(sBlane + C * 64 * 8);  // ds_read_b128 imm
        a0 = __builtin_amdgcn_mfma_f32_16x16x32_f16(make_frag<C>(p0), bf, a0, 0, 0, 0);
        a1 = __builtin_amdgcn_mfma_f32_16x16x32_f16(make_frag<C>(p1), bf, a1, 0, 0, 0);
    }()), ...);
}

// ---------- patch from LDS x-tile: 25 imm-offset ds_reads + 13 cvt ----------
__device__ __forceinline__ void patch_from_lds(const float* xt, int base,
                                               half2 (&pd2)[13]) {
    float pf[26];
    pf[25] = 0.f;
    #pragma unroll
    for (int kh = 0; kh < 5; ++kh)
        #pragma unroll
        for (int kw = 0; kw < 5; ++kw)
            pf[kh * 5 + kw] = xt[base + kh * XW + kw];
    #pragma unroll
    for (int t = 0; t < 13; ++t) pd2[t] = pk(pf[2 * t], pf[2 * t + 1]);
}

// ---------- main kernel: 512 thr = 8 waves = 8 rows x 32 cols ----------
__global__ __launch_bounds__(512, 4) void convquad_gemm(
    const float* __restrict__ x,       // (8,250,250,4)
    const float* __restrict__ bias,    // (16,)
    const _Float16* __restrict__ fragB,
    float* __restrict__ out)           // (8,250,250,16)
{
    __shared__ float xt[4 * XSZ];                     // 6,912 B: [c][hh][ww]
    __shared__ __align__(16) _Float16 sB[NFRAG * 8];  // 50,176 B

    const int w0 = blockIdx.x * TW;
    const int h0 = blockIdx.y * TH;
    const int b  = blockIdx.z;

    {   // coalesced 50KB B copy: global (L2-hot) -> LDS (~6 float4/thread)
        const float4* src = (const float4*)fragB;
        float4* dst = (float4*)sB;
        #pragma unroll
        for (int t = threadIdx.x; t < NFRAG * 8 / 8; t += 512) dst[t] = src[t];
    }

    // ---- stage haloed x-tile (borders zeroed -> no masks later) ----
    {
        const int p = threadIdx.x;
        if (p < XSZ) {
            const int hh = p / XW, ww = p % XW;
            const int r = h0 + hh - 2, c = w0 + ww - 2;
            float4 v = make_float4(0.f, 0.f, 0.f, 0.f);
            if ((unsigned)r < (unsigned)HH && (unsigned)c < (unsigned)WW)
                v = ((const float4*)x)[(b * HH + r) * WW + c];
            xt[0 * XSZ + p] = v.x;
            xt[1 * XSZ + p] = v.y;
            xt[2 * XSZ + p] = v.z;
            xt[3 * XSZ + p] = v.w;
        }
    }
    __syncthreads();

    const int lane = threadIdx.x & 63;
    const int wave = threadIdx.x >> 6;   // row within tile
    const int m = lane & 15;             // pixel within 16-col segment; also o
    const int q = lane >> 4;             // channel for A; row-quad for D

    // two 16-col segments per wave (cols 0..15, 16..31)
    const int base0 = q * XSZ + wave * XW + m;
    half2 pd0[13], pd1[13];
    patch_from_lds(xt, base0,      pd0);
    patch_from_lds(xt, base0 + 16, pd1);

    const float bo = bias[m];
    floatx4 acc0 = {bo, bo, bo, bo};
    floatx4 acc1 = acc0;

    gemm_all(pd0, pd1, sB + lane * 8, acc0, acc1,
             std::make_index_sequence<NCHUNK>{});

    // ---- store: pixel w-offset = seg*16 + q*4 + r, o = m ----
    const int h = h0 + wave;
    if (h < HH) {
        const int rowbase = (b * HH + h) * WW;
        #pragma unroll
        for (int r = 0; r < 4; ++r) {
            const int wA = w0 + q * 4 + r;
            if (wA < WW) out[(rowbase + wA) * NF + m] = acc0[r];
            const int wB = w0 + 16 + q * 4 + r;
            if (wB < WW) out[(rowbase + wB) * NF + m] = acc1[r];
        }
    }
}

extern "C" void kernel_launch(void* const* d_in, const int* in_sizes, int n_in,
                              void* d_out, int out_size, void* d_ws, size_t ws_size,
                              hipStream_t stream) {
    const float* x      = (const float*)d_in[0];
    const float* lin_w  = (const float*)d_in[1];
    const float* quad_w = (const float*)d_in[2];
    const float* bias   = (const float*)d_in[3];
    float* out = (float*)d_out;
    _Float16* fragB = (_Float16*)d_ws;   // 50,176 B

    prep_frags<<<dim3(NCHUNK), dim3(64), 0, stream>>>(lin_w, quad_w, fragB);

    dim3 grid((WW + TW - 1) / TW, (HH + TH - 1) / TH, BB);   // 8 x 32 x 8 = 2048
    convquad_gemm<<<grid, dim3(512), 0, stream>>>(x, bias, fragB, out);
}